// Round 10
// baseline (344.355 us; speedup 1.0000x reference)
//
#include <hip/hip_runtime.h>
#include <hip/hip_bf16.h>
#include <hip/hip_fp16.h>
#include <stdint.h>

#define N_NODESC 25000
#define N_EDGESC 400000
#define N_GRAPHSC 64
#define F_INC 128
#define HIDC 512
#define PSTRIDE 1600000   // elements per 64-col panel: 25000*64
#define EMETA_CAP 775008  // 400000 + 25000*15, padded to 16 per node

typedef __attribute__((ext_vector_type(8))) short short8;
typedef __attribute__((ext_vector_type(4))) float f32x4;

__device__ __forceinline__ float bf2f(unsigned short u) {
  return __uint_as_float(((unsigned)u) << 16);
}
__device__ __forceinline__ unsigned short f2bf(float f) {
  unsigned u = __float_as_uint(f);
  u += 0x7fffu + ((u >> 16) & 1u);
  return (unsigned short)(u >> 16);
}

// ================= prep: zero deg/gsum, x -> bf16 PANEL-MAJOR (1 launch) ==========
__global__ void prep_kernel(const float* __restrict__ x, unsigned short* __restrict__ xp,
                            int* __restrict__ deg, float* __restrict__ gsum) {
  int blk = blockIdx.x, t = threadIdx.x;
  if (blk < 98) {
    int i = blk * 256 + t;
    if (i < N_NODESC) deg[i] = 0;
  } else if (blk < 3223) {                       // 3125 blocks: 3.2M elems / 4
    int idx = ((blk - 98) * 256 + t) * 4;        // row-major element index
    int node = idx >> 7;
    int col = idx & 127;
    float4 v = *(const float4*)(x + idx);
    ushort4 o;
    o.x = f2bf(v.x); o.y = f2bf(v.y); o.z = f2bf(v.z); o.w = f2bf(v.w);
    *(ushort4*)(xp + (size_t)(col >> 6) * PSTRIDE + (size_t)node * 64 + (col & 63)) = o;
  } else {                                       // 128 blocks: gsum 64x512
    int i = (blk - 3223) * 256 + t;
    if (i < N_GRAPHSC * HIDC) gsum[i] = 0.f;
  }
}

// ================= weight transpose via LDS tiles (coalesced both sides) ==========
__global__ __launch_bounds__(256)
void wt_kernel(const float* __restrict__ W1rel, const float* __restrict__ W1root,
               const float* __restrict__ W2rel, const float* __restrict__ W2root,
               unsigned short* __restrict__ W1T, unsigned short* __restrict__ W2T) {
  __shared__ float tile[64][65];
  int blk = blockIdx.x;
  const float* src;
  unsigned short* dst;
  int n0, k0, Kout;
  if (blk < 128) {                               // W2: k-tiles 16, n-tiles 8
    int kt = blk >> 3, nt = blk & 7;
    k0 = kt * 64; n0 = nt * 64;
    src = (k0 < 512) ? (W2rel + (size_t)k0 * 512) : (W2root + (size_t)(k0 - 512) * 512);
    dst = W2T; Kout = 1024;
  } else {                                       // W1: k-tiles 4, n-tiles 8
    int b = blk - 128;
    int kt = b >> 3, nt = b & 7;
    k0 = kt * 64; n0 = nt * 64;
    src = (k0 < 128) ? (W1rel + (size_t)k0 * 512) : (W1root + (size_t)(k0 - 128) * 512);
    dst = W1T; Kout = 256;
  }
  int c = threadIdx.x & 63;
  int r4 = threadIdx.x >> 6;
#pragma unroll
  for (int rr = 0; rr < 64; rr += 4) {
    int row = rr + r4;
    tile[c][row] = src[(size_t)row * 512 + n0 + c];
  }
  __syncthreads();
#pragma unroll
  for (int rr = 0; rr < 64; rr += 4) {
    int nrow = rr + r4;
    dst[(size_t)(n0 + nrow) * Kout + k0 + c] = f2bf(tile[nrow][c]);
  }
}

// ================= CSR build (node lists padded to multiples of 16) ===============
__global__ void deg_kernel(const int* __restrict__ ei, int* __restrict__ deg) {
  int e = blockIdx.x * blockDim.x + threadIdx.x;
  if (e >= N_EDGESC) return;
  atomicAdd(&deg[ei[N_EDGESC + e]], 1);
}

__global__ __launch_bounds__(1024)
void scan_kernel(const int* __restrict__ deg, int* __restrict__ indptr, int* __restrict__ cursor) {
  __shared__ int sums[1024];
  const int t = threadIdx.x;
  const int CH = (N_NODESC + 1023) / 1024;  // 25
  const int base = t * CH;
  int s = 0;
  for (int i = 0; i < CH; ++i) {
    int idx = base + i;
    if (idx < N_NODESC) s += (deg[idx] + 15) & ~15;   // padded degree
  }
  sums[t] = s;
  __syncthreads();
  for (int off = 1; off < 1024; off <<= 1) {
    int v = (t >= off) ? sums[t - off] : 0;
    __syncthreads();
    sums[t] += v;
    __syncthreads();
  }
  int run = (t > 0) ? sums[t - 1] : 0;
  for (int i = 0; i < CH; ++i) {
    int idx = base + i;
    if (idx < N_NODESC) {
      indptr[idx] = run;
      cursor[idx] = run;
      run += (deg[idx] + 15) & ~15;
    }
  }
  if (t == 0) indptr[N_NODESC] = sums[1023];
}

// packed edge meta: src (16b) | fp16 weight (16b). Pad slots stay 0 (w=+0 -> no-op).
__global__ void fill_kernel(const int* __restrict__ ei, const float* __restrict__ ea,
                            int* __restrict__ cursor, unsigned* __restrict__ emeta) {
  int e = blockIdx.x * blockDim.x + threadIdx.x;
  if (e >= N_EDGESC) return;
  int dst = ei[N_EDGESC + e];
  int pos = atomicAdd(&cursor[dst], 1);
  unsigned short hw = __half_as_ushort(__float2half_rn(ea[e]));
  emeta[pos] = (unsigned)ei[e] | ((unsigned)hw << 16);
}

// ================= panel-major CSR gather (L2-blocked, 8 edges per load) ==========
// feat/outp: bf16 [P][25000][64] (row = 128B). panel = blk & (P-1) -> XCD-pinned.
// One wave per (panel,node); 8 lanes per edge (uint4 = 16B/lane = full 128B row),
// 8 edges per feature-load instruction. Meta: coalesced 64-edge load + shfl.
// 32-bit u24 offsets from wave-uniform panel base. Degree padded to 16.
__global__ __launch_bounds__(256)
void agg_gather_p(const unsigned short* __restrict__ feat, const int* __restrict__ indptr,
                  const unsigned* __restrict__ emeta, unsigned short* __restrict__ outp,
                  int lgP) {
  int panel = blockIdx.x & ((1 << lgP) - 1);
  int node = (blockIdx.x >> lgP) * 4 + (threadIdx.x >> 6);
  if (node >= N_NODESC) return;
  int lane = threadIdx.x & 63;
  int g = lane >> 3;         // group: which of 8 concurrent edges
  int c8 = lane & 7;         // 8 cols per lane (uint4)
  int beg = indptr[node], end = indptr[node + 1];
  int degp = end - beg;      // multiple of 16 (pad meta = 0 -> w=+0)
  const unsigned* mp = emeta + beg;
  const char* fb = (const char*)(feat + (size_t)panel * PSTRIDE);
  unsigned coff = c8 * 16;   // byte offset within the 128B row
  float a0 = 0.f, a1 = 0.f, a2 = 0.f, a3 = 0.f;
  float a4 = 0.f, a5 = 0.f, a6 = 0.f, a7 = 0.f;
  for (int j64 = 0; j64 < degp; j64 += 64) {
    int cnt = degp - j64;
    if (cnt > 64) cnt = 64;
    unsigned mload = (lane < cnt) ? mp[j64 + lane] : 0u;
    for (int jj = 0; jj < cnt; jj += 16) {
      unsigned mA = __shfl(mload, jj + g);
      unsigned mB = __shfl(mload, jj + 8 + g);
      unsigned offA = (mA & 0xffffu) * 128u + coff;
      unsigned offB = (mB & 0xffffu) * 128u + coff;
      uint4 vA = *(const uint4*)(fb + offA);
      uint4 vB = *(const uint4*)(fb + offB);
      float wA = __half2float(__ushort_as_half((unsigned short)(mA >> 16)));
      float wB = __half2float(__ushort_as_half((unsigned short)(mB >> 16)));
      a0 += __uint_as_float(vA.x << 16) * wA;
      a1 += __uint_as_float(vA.x & 0xffff0000u) * wA;
      a2 += __uint_as_float(vA.y << 16) * wA;
      a3 += __uint_as_float(vA.y & 0xffff0000u) * wA;
      a4 += __uint_as_float(vA.z << 16) * wA;
      a5 += __uint_as_float(vA.z & 0xffff0000u) * wA;
      a6 += __uint_as_float(vA.w << 16) * wA;
      a7 += __uint_as_float(vA.w & 0xffff0000u) * wA;
      a0 += __uint_as_float(vB.x << 16) * wB;
      a1 += __uint_as_float(vB.x & 0xffff0000u) * wB;
      a2 += __uint_as_float(vB.y << 16) * wB;
      a3 += __uint_as_float(vB.y & 0xffff0000u) * wB;
      a4 += __uint_as_float(vB.z << 16) * wB;
      a5 += __uint_as_float(vB.z & 0xffff0000u) * wB;
      a6 += __uint_as_float(vB.w << 16) * wB;
      a7 += __uint_as_float(vB.w & 0xffff0000u) * wB;
    }
  }
  // reduce across the 8 groups (same cols, different edges): xor 8, 16, 32
#pragma unroll
  for (int d = 8; d <= 32; d <<= 1) {
    a0 += __shfl_xor(a0, d); a1 += __shfl_xor(a1, d);
    a2 += __shfl_xor(a2, d); a3 += __shfl_xor(a3, d);
    a4 += __shfl_xor(a4, d); a5 += __shfl_xor(a5, d);
    a6 += __shfl_xor(a6, d); a7 += __shfl_xor(a7, d);
  }
  if (g == 0) {
    short8 o;
    o[0] = (short)f2bf(a0); o[1] = (short)f2bf(a1); o[2] = (short)f2bf(a2); o[3] = (short)f2bf(a3);
    o[4] = (short)f2bf(a4); o[5] = (short)f2bf(a5); o[6] = (short)f2bf(a6); o[7] = (short)f2bf(a7);
    *(short8*)(outp + (size_t)panel * PSTRIDE + (size_t)node * 64 + c8 * 8) = o;
  }
}

// ---------------- bf16 MFMA GEMM (A operands PANEL-MAJOR): h1p = relu([A0|A1]@BT^T + b)
__global__ __launch_bounds__(256, 3)
void gemm_bt_relu(const short* __restrict__ A0, const short* __restrict__ A1,
                  const short* __restrict__ BT, const float* __restrict__ bias,
                  unsigned short* __restrict__ Outp, int M, int S) {
  const int K = 2 * S;
  __shared__ __align__(16) short As[128 * 64];
  __shared__ __align__(16) short Bs[128 * 64];
  const int m0 = blockIdx.x * 128;
  const int n0 = blockIdx.y * 128;
  const int tid = threadIdx.x;
  const int wave = tid >> 6;
  const int lane = tid & 63;
  const int quad = lane >> 4;
  const int r = lane & 15;
  const int wm = (wave >> 1) * 64;
  const int wn = (wave & 1) * 64;

  f32x4 acc[4][4] = {};

  const int nk = K >> 6;
  for (int kt = 0; kt < nk; ++kt) {
    const int kbase = kt << 6;
    const short* Ab;
    int koff;
    if (kbase < S) { Ab = A0; koff = kbase; } else { Ab = A1; koff = kbase - S; }
    const short* Apan = Ab + (size_t)(koff >> 6) * PSTRIDE;
#pragma unroll
    for (int i = 0; i < 4; ++i) {
      int s = ((wave * 4 + i) << 6) + lane;
      int row = s >> 3;
      int c = (s & 7) ^ (row & 7);
      int rg = m0 + row; if (rg > M - 1) rg = M - 1;
      const short* gp = Apan + (size_t)rg * 64 + (c << 3);
      __builtin_amdgcn_global_load_lds((const __attribute__((address_space(1))) void*)gp,
                                       (__attribute__((address_space(3))) void*)&As[(wave * 4 + i) * 512],
                                       16, 0, 0);
    }
#pragma unroll
    for (int i = 0; i < 4; ++i) {
      int s = ((wave * 4 + i) << 6) + lane;
      int row = s >> 3;
      int c = (s & 7) ^ (row & 7);
      const short* gp = BT + (size_t)(n0 + row) * K + kbase + (c << 3);
      __builtin_amdgcn_global_load_lds((const __attribute__((address_space(1))) void*)gp,
                                       (__attribute__((address_space(3))) void*)&Bs[(wave * 4 + i) * 512],
                                       16, 0, 0);
    }
    __syncthreads();
#pragma unroll
    for (int ks = 0; ks < 2; ++ks) {
      short8 af[4], bfr[4];
#pragma unroll
      for (int tm = 0; tm < 4; ++tm) {
        int ml = wm + tm * 16 + r;
        int c = (ks << 2) + quad;
        int slot = ml * 8 + (c ^ (ml & 7));
        af[tm] = *(const short8*)&As[slot * 8];
      }
#pragma unroll
      for (int tn = 0; tn < 4; ++tn) {
        int nl = wn + tn * 16 + r;
        int c = (ks << 2) + quad;
        int slot = nl * 8 + (c ^ (nl & 7));
        bfr[tn] = *(const short8*)&Bs[slot * 8];
      }
#pragma unroll
      for (int tm = 0; tm < 4; ++tm)
#pragma unroll
        for (int tn = 0; tn < 4; ++tn)
          acc[tm][tn] = __builtin_amdgcn_mfma_f32_16x16x32_bf16(af[tm], bfr[tn], acc[tm][tn], 0, 0, 0);
    }
    __syncthreads();
  }

#pragma unroll
  for (int tm = 0; tm < 4; ++tm) {
    int rowb = m0 + wm + tm * 16 + quad * 4;
#pragma unroll
    for (int tn = 0; tn < 4; ++tn) {
      int col = n0 + wn + tn * 16 + r;
      float bv = bias[col];
      unsigned short* obase = Outp + (size_t)(col >> 6) * PSTRIDE + (col & 63);
#pragma unroll
      for (int reg = 0; reg < 4; ++reg) {
        int rr = rowb + reg;
        if (rr < M) {
          float v = acc[tm][tn][reg] + bv;
          v = v > 0.f ? v : 0.f;
          obase[(size_t)rr * 64] = f2bf(v);
        }
      }
    }
  }
}

// ---------------- GEMM2 + fused mean-pool (A panel-major): gsum += per-graph col sums
__global__ __launch_bounds__(256, 3)
void gemm_bt_pool(const short* __restrict__ A0, const short* __restrict__ A1,
                  const short* __restrict__ BT, const float* __restrict__ bias,
                  const int* __restrict__ batch, float* __restrict__ gsum, int M, int S) {
  const int K = 2 * S;
  __shared__ __align__(16) short As[128 * 64];
  __shared__ __align__(16) short Bs[128 * 64];
  const int m0 = blockIdx.x * 128;
  const int n0 = blockIdx.y * 128;
  const int tid = threadIdx.x;
  const int wave = tid >> 6;
  const int lane = tid & 63;
  const int quad = lane >> 4;
  const int r = lane & 15;
  const int wm = (wave >> 1) * 64;
  const int wn = (wave & 1) * 64;

  f32x4 acc[4][4] = {};

  const int nk = K >> 6;
  for (int kt = 0; kt < nk; ++kt) {
    const int kbase = kt << 6;
    const short* Ab;
    int koff;
    if (kbase < S) { Ab = A0; koff = kbase; } else { Ab = A1; koff = kbase - S; }
    const short* Apan = Ab + (size_t)(koff >> 6) * PSTRIDE;
#pragma unroll
    for (int i = 0; i < 4; ++i) {
      int s = ((wave * 4 + i) << 6) + lane;
      int row = s >> 3;
      int c = (s & 7) ^ (row & 7);
      int rg = m0 + row; if (rg > M - 1) rg = M - 1;
      const short* gp = Apan + (size_t)rg * 64 + (c << 3);
      __builtin_amdgcn_global_load_lds((const __attribute__((address_space(1))) void*)gp,
                                       (__attribute__((address_space(3))) void*)&As[(wave * 4 + i) * 512],
                                       16, 0, 0);
    }
#pragma unroll
    for (int i = 0; i < 4; ++i) {
      int s = ((wave * 4 + i) << 6) + lane;
      int row = s >> 3;
      int c = (s & 7) ^ (row & 7);
      const short* gp = BT + (size_t)(n0 + row) * K + kbase + (c << 3);
      __builtin_amdgcn_global_load_lds((const __attribute__((address_space(1))) void*)gp,
                                       (__attribute__((address_space(3))) void*)&Bs[(wave * 4 + i) * 512],
                                       16, 0, 0);
    }
    __syncthreads();
#pragma unroll
    for (int ks = 0; ks < 2; ++ks) {
      short8 af[4], bfr[4];
#pragma unroll
      for (int tm = 0; tm < 4; ++tm) {
        int ml = wm + tm * 16 + r;
        int c = (ks << 2) + quad;
        int slot = ml * 8 + (c ^ (ml & 7));
        af[tm] = *(const short8*)&As[slot * 8];
      }
#pragma unroll
      for (int tn = 0; tn < 4; ++tn) {
        int nl = wn + tn * 16 + r;
        int c = (ks << 2) + quad;
        int slot = nl * 8 + (c ^ (nl & 7));
        bfr[tn] = *(const short8*)&Bs[slot * 8];
      }
#pragma unroll
      for (int tm = 0; tm < 4; ++tm)
#pragma unroll
        for (int tn = 0; tn < 4; ++tn)
          acc[tm][tn] = __builtin_amdgcn_mfma_f32_16x16x32_bf16(af[tm], bfr[tn], acc[tm][tn], 0, 0, 0);
    }
    __syncthreads();
  }

  // epilogue: relu(+bias), zero invalid rows, per-graph column sums -> atomicAdd(gsum)
  int gid[4][4];
#pragma unroll
  for (int tm = 0; tm < 4; ++tm) {
    int rowb = m0 + wm + tm * 16 + quad * 4;
#pragma unroll
    for (int reg = 0; reg < 4; ++reg) {
      int rr = rowb + reg;
      gid[tm][reg] = batch[rr < M ? rr : (M - 1)];
    }
#pragma unroll
    for (int tn = 0; tn < 4; ++tn) {
      float bv = bias[n0 + wn + tn * 16 + r];
#pragma unroll
      for (int reg = 0; reg < 4; ++reg) {
        int rr = rowb + reg;
        float v = acc[tm][tn][reg] + bv;
        v = v > 0.f ? v : 0.f;
        acc[tm][tn][reg] = (rr < M) ? v : 0.f;
      }
    }
  }
  int g_lo = batch[m0 < M ? m0 : (M - 1)];
  int g_hi = batch[(m0 + 127) < M ? (m0 + 127) : (M - 1)];
  for (int g = g_lo; g <= g_hi; ++g) {
#pragma unroll
    for (int tn = 0; tn < 4; ++tn) {
      float s = 0.f;
#pragma unroll
      for (int tm = 0; tm < 4; ++tm)
#pragma unroll
        for (int reg = 0; reg < 4; ++reg)
          s += (gid[tm][reg] == g) ? acc[tm][tn][reg] : 0.f;
      s += __shfl_xor(s, 16);
      s += __shfl_xor(s, 32);
      if (quad == 0)
        atomicAdd(&gsum[(size_t)g * HIDC + n0 + wn + tn * 16 + r], s);
    }
  }
}

// ---------------- MLP head (256 threads: 4-way split over the 512-dim input)
__global__ __launch_bounds__(256)
void mlp_kernel(const float* __restrict__ gsum, const int* __restrict__ batch,
                const float* __restrict__ Wl1, const float* __restrict__ bl1,
                const float* __restrict__ Wl2, const float* __restrict__ bl2,
                const float* __restrict__ Wl3, const float* __restrict__ bl3,
                float* __restrict__ out) {
  int gi = blockIdx.x;
  int t = threadIdx.x;
  int unit = t & 63;
  int part = t >> 6;  // 4 parts of 128
  __shared__ float red[4][64];
  __shared__ float h1s[64];
  __shared__ float h2s[16];
  int lo = 0, hi = N_NODESC;
  while (lo < hi) { int mid = (lo + hi) >> 1; if (batch[mid] < gi) lo = mid + 1; else hi = mid; }
  int start = lo;
  hi = N_NODESC;
  while (lo < hi) { int mid = (lo + hi) >> 1; if (batch[mid] < gi + 1) lo = mid + 1; else hi = mid; }
  float inv = 1.0f / fmaxf((float)(lo - start), 1.0f);
  const float* gr = gsum + gi * HIDC;
  float acc = 0.f;
  for (int j = part * 128; j < (part + 1) * 128; ++j)
    acc += gr[j] * Wl1[j * 64 + unit];
  red[part][unit] = acc;
  __syncthreads();
  if (t < 64) {
    float a = bl1[t] + (red[0][t] + red[1][t] + red[2][t] + red[3][t]) * inv;
    h1s[t] = fmaxf(a, 0.f);
  }
  __syncthreads();
  if (t < 16) {
    float a = bl2[t];
    for (int j = 0; j < 64; ++j) a += h1s[j] * Wl2[j * 16 + t];
    h2s[t] = fmaxf(a, 0.f);
  }
  __syncthreads();
  if (t == 0) {
    float a = bl3[0];
    for (int j = 0; j < 16; ++j) a += h2s[j] * Wl3[j];
    out[gi] = a;
  }
}

extern "C" void kernel_launch(void* const* d_in, const int* in_sizes, int n_in,
                              void* d_out, int out_size, void* d_ws, size_t ws_size,
                              hipStream_t stream) {
  const float* x      = (const float*)d_in[0];
  const int*   ei     = (const int*)d_in[1];
  const float* ea     = (const float*)d_in[2];
  const int*   batch  = (const int*)d_in[3];
  const float* W1rel  = (const float*)d_in[4];
  const float* b1     = (const float*)d_in[5];
  const float* W1root = (const float*)d_in[6];
  const float* W2rel  = (const float*)d_in[7];
  const float* b2     = (const float*)d_in[8];
  const float* W2root = (const float*)d_in[9];
  const float* Wl1    = (const float*)d_in[10];
  const float* bl1    = (const float*)d_in[11];
  const float* Wl2    = (const float*)d_in[12];
  const float* bl2    = (const float*)d_in[13];
  const float* Wl3    = (const float*)d_in[14];
  const float* bl3    = (const float*)d_in[15];
  float* out = (float*)d_out;

  // workspace layout (bytes, 16B-aligned). All node features PANEL-MAJOR [P][25000][64].
  char* ws = (char*)d_ws;
  unsigned short* xp     = (unsigned short*)(ws + 0);           //  6.4 MB (2 panels)
  unsigned short* agg1p  = (unsigned short*)(ws + 6400000);     //  6.4 MB (2 panels)
  unsigned short* h1p    = (unsigned short*)(ws + 12800000);    // 25.6 MB (8 panels)
  unsigned short* agg2p  = (unsigned short*)(ws + 38400000);    // 25.6 MB (8 panels)
  unsigned short* W1T    = (unsigned short*)(ws + 64000000);    // 256 KB
  unsigned short* W2T    = (unsigned short*)(ws + 64262144);    //   1 MB
  float*          gsum   = (float*)(ws + 65310720);             // 128 KB
  int*            deg    = (int*)(ws + 65441792);               // 100 KB
  int*            cursor = (int*)(ws + 65541792);               // 100 KB
  int*            indptr = (int*)(ws + 65641792);               // 100 KB+16
  unsigned*       emeta  = (unsigned*)(ws + 65741808);          //  3.1 MB (padded CSR)

  // 0) prep (zero deg+gsum, x->bf16 panels) + weight transposes + CSR build (padded)
  prep_kernel<<<3351, 256, 0, stream>>>(x, xp, deg, gsum);
  wt_kernel<<<160, 256, 0, stream>>>(W1rel, W1root, W2rel, W2root, W1T, W2T);
  deg_kernel<<<(N_EDGESC + 255) / 256, 256, 0, stream>>>(ei, deg);
  hipMemsetAsync(emeta, 0, EMETA_CAP * sizeof(unsigned), stream);
  scan_kernel<<<1, 1024, 0, stream>>>(deg, indptr, cursor);
  fill_kernel<<<(N_EDGESC + 255) / 256, 256, 0, stream>>>(ei, ea, cursor, emeta);

  // 1) layer-1 aggregation: 2 panels (panel = blk&1)
  agg_gather_p<<<((N_NODESC + 3) / 4) * 2, 256, 0, stream>>>(xp, indptr, emeta, agg1p, 1);

  // 2) GEMM1: h1p = relu([agg1|x] @ [W1rel;W1root] + b1)   (M=25000, K=256, N=512)
  dim3 gg((N_NODESC + 127) / 128, 4);
  gemm_bt_relu<<<gg, 256, 0, stream>>>((const short*)agg1p, (const short*)xp,
                                       (const short*)W1T, b1, h1p, N_NODESC, 128);

  // 3) layer-2 aggregation: 8 panels (panel = blk&7 -> one panel per XCD, 3.2MB L2-resident)
  agg_gather_p<<<((N_NODESC + 3) / 4) * 8, 256, 0, stream>>>(h1p, indptr, emeta, agg2p, 3);

  // 4) GEMM2 + fused mean-pool
  gemm_bt_pool<<<gg, 256, 0, stream>>>((const short*)agg2p, (const short*)h1p,
                                       (const short*)W2T, b2, batch, gsum, N_NODESC, 512);

  // 5) MLP head (divides by counts)
  mlp_kernel<<<N_GRAPHSC, 256, 0, stream>>>(gsum, batch, Wl1, bl1, Wl2, bl2, Wl3, bl3, out);
}

// Round 11
// 298.471 us; speedup vs baseline: 1.1537x; 1.1537x over previous
//
#include <hip/hip_runtime.h>
#include <hip/hip_bf16.h>
#include <hip/hip_fp16.h>
#include <stdint.h>

#define N_NODESC 25000
#define N_EDGESC 400000
#define N_GRAPHSC 64
#define F_INC 128
#define HIDC 512
#define PSTRIDE 1600000   // elements per 64-col panel: 25000*64

typedef __attribute__((ext_vector_type(8))) short short8;
typedef __attribute__((ext_vector_type(4))) float f32x4;

__device__ __forceinline__ float bf2f(unsigned short u) {
  return __uint_as_float(((unsigned)u) << 16);
}
__device__ __forceinline__ unsigned short f2bf(float f) {
  unsigned u = __float_as_uint(f);
  u += 0x7fffu + ((u >> 16) & 1u);
  return (unsigned short)(u >> 16);
}

// ================= prep: zero deg/gsum, x -> bf16 PANEL-MAJOR (1 launch) ==========
__global__ void prep_kernel(const float* __restrict__ x, unsigned short* __restrict__ xp,
                            int* __restrict__ deg, float* __restrict__ gsum) {
  int blk = blockIdx.x, t = threadIdx.x;
  if (blk < 98) {
    int i = blk * 256 + t;
    if (i < N_NODESC) deg[i] = 0;
  } else if (blk < 3223) {                       // 3125 blocks: 3.2M elems / 4
    int idx = ((blk - 98) * 256 + t) * 4;        // row-major element index
    int node = idx >> 7;
    int col = idx & 127;
    float4 v = *(const float4*)(x + idx);
    ushort4 o;
    o.x = f2bf(v.x); o.y = f2bf(v.y); o.z = f2bf(v.z); o.w = f2bf(v.w);
    *(ushort4*)(xp + (size_t)(col >> 6) * PSTRIDE + (size_t)node * 64 + (col & 63)) = o;
  } else {                                       // 128 blocks: gsum 64x512
    int i = (blk - 3223) * 256 + t;
    if (i < N_GRAPHSC * HIDC) gsum[i] = 0.f;
  }
}

// ================= weight transpose via LDS tiles (coalesced both sides) ==========
__global__ __launch_bounds__(256)
void wt_kernel(const float* __restrict__ W1rel, const float* __restrict__ W1root,
               const float* __restrict__ W2rel, const float* __restrict__ W2root,
               unsigned short* __restrict__ W1T, unsigned short* __restrict__ W2T) {
  __shared__ float tile[64][65];
  int blk = blockIdx.x;
  const float* src;
  unsigned short* dst;
  int n0, k0, Kout;
  if (blk < 128) {                               // W2: k-tiles 16, n-tiles 8
    int kt = blk >> 3, nt = blk & 7;
    k0 = kt * 64; n0 = nt * 64;
    src = (k0 < 512) ? (W2rel + (size_t)k0 * 512) : (W2root + (size_t)(k0 - 512) * 512);
    dst = W2T; Kout = 1024;
  } else {                                       // W1: k-tiles 4, n-tiles 8
    int b = blk - 128;
    int kt = b >> 3, nt = b & 7;
    k0 = kt * 64; n0 = nt * 64;
    src = (k0 < 128) ? (W1rel + (size_t)k0 * 512) : (W1root + (size_t)(k0 - 128) * 512);
    dst = W1T; Kout = 256;
  }
  int c = threadIdx.x & 63;
  int r4 = threadIdx.x >> 6;
#pragma unroll
  for (int rr = 0; rr < 64; rr += 4) {
    int row = rr + r4;
    tile[c][row] = src[(size_t)row * 512 + n0 + c];
  }
  __syncthreads();
#pragma unroll
  for (int rr = 0; rr < 64; rr += 4) {
    int nrow = rr + r4;
    dst[(size_t)(n0 + nrow) * Kout + k0 + c] = f2bf(tile[nrow][c]);
  }
}

// ================= CSR build =================
__global__ void deg_kernel(const int* __restrict__ ei, int* __restrict__ deg) {
  int e = blockIdx.x * blockDim.x + threadIdx.x;
  if (e >= N_EDGESC) return;
  atomicAdd(&deg[ei[N_EDGESC + e]], 1);
}

// single-block: exclusive scan of deg -> indptr/cursor, PLUS counting sort of node ids
// by degree (LDS histogram over 256 bins) -> sorted[25000].
__global__ __launch_bounds__(1024)
void scan_kernel(const int* __restrict__ deg, int* __restrict__ indptr, int* __restrict__ cursor,
                 int* __restrict__ sorted) {
  __shared__ int sums[1024];
  __shared__ int bins[256];
  __shared__ int binptr[256];
  const int t = threadIdx.x;
  const int CH = (N_NODESC + 1023) / 1024;  // 25
  const int base = t * CH;
  if (t < 256) bins[t] = 0;
  __syncthreads();
  int dl[CH];
  int s = 0;
  for (int i = 0; i < CH; ++i) {
    int idx = base + i;
    int d = (idx < N_NODESC) ? deg[idx] : -1;
    dl[i] = d;
    if (d >= 0) {
      s += d;
      atomicAdd(&bins[d > 255 ? 255 : d], 1);
    }
  }
  sums[t] = s;
  __syncthreads();
  for (int off = 1; off < 1024; off <<= 1) {
    int v = (t >= off) ? sums[t - off] : 0;
    __syncthreads();
    sums[t] += v;
    __syncthreads();
  }
  if (t == 0) {
    int run = 0;
    for (int b = 0; b < 256; ++b) { binptr[b] = run; run += bins[b]; }
  }
  __syncthreads();
  int run = (t > 0) ? sums[t - 1] : 0;
  for (int i = 0; i < CH; ++i) {
    int idx = base + i;
    if (idx < N_NODESC) {
      indptr[idx] = run;
      cursor[idx] = run;
      run += dl[i];
      int pos = atomicAdd(&binptr[dl[i] > 255 ? 255 : dl[i]], 1);
      sorted[pos] = idx;
    }
  }
  if (t == 0) indptr[N_NODESC] = sums[1023];
}

// packed edge meta: src (16b) | fp16 weight (16b)
__global__ void fill_kernel(const int* __restrict__ ei, const float* __restrict__ ea,
                            int* __restrict__ cursor, unsigned* __restrict__ emeta) {
  int e = blockIdx.x * blockDim.x + threadIdx.x;
  if (e >= N_EDGESC) return;
  int dst = ei[N_EDGESC + e];
  int pos = atomicAdd(&cursor[dst], 1);
  unsigned short hw = __half_as_ushort(__float2half_rn(ea[e]));
  emeta[pos] = (unsigned)ei[e] | ((unsigned)hw << 16);
}

// ================= panel-major CSR gather (L2-blocked, 8 nodes per wave) ==========
// feat/outp: bf16 [P][25000][64] (row = 128B). panel = blk & (P-1) -> XCD-pinned.
// Wave = 8 groups x 8 lanes; group g owns node sorted[base+g] ALONE (no cross-lane
// reduce). Each lane holds 8 cols (uint4 = 16B); one load instruction covers all 8
// groups' rows. Nodes degree-sorted -> groups in a wave have near-equal trip counts.
__global__ __launch_bounds__(256)
void agg_gather_s(const unsigned short* __restrict__ feat, const int* __restrict__ indptr,
                  const unsigned* __restrict__ emeta, const int* __restrict__ sorted,
                  unsigned short* __restrict__ outp, int lgP) {
  int panel = blockIdx.x & ((1 << lgP) - 1);
  int nidx = (blockIdx.x >> lgP) * 32 + (threadIdx.x >> 3);   // 32 node-slots / block
  if (nidx >= N_NODESC) return;
  int c8 = threadIdx.x & 7;
  int node = sorted[nidx];
  int beg = indptr[node];
  int deg = indptr[node + 1] - beg;
  const unsigned* mp = emeta + beg;
  const char* fb = (const char*)(feat + (size_t)panel * PSTRIDE);
  unsigned coff = c8 * 16u;
  float a0 = 0.f, a1 = 0.f, a2 = 0.f, a3 = 0.f;
  float a4 = 0.f, a5 = 0.f, a6 = 0.f, a7 = 0.f;
  int j = 0;
  for (; j + 2 <= deg; j += 2) {
    unsigned mA = mp[j];
    unsigned mB = mp[j + 1];
    uint4 vA = *(const uint4*)(fb + (mA & 0xffffu) * 128u + coff);
    uint4 vB = *(const uint4*)(fb + (mB & 0xffffu) * 128u + coff);
    float wA = __half2float(__ushort_as_half((unsigned short)(mA >> 16)));
    float wB = __half2float(__ushort_as_half((unsigned short)(mB >> 16)));
    a0 += __uint_as_float(vA.x << 16) * wA;
    a1 += __uint_as_float(vA.x & 0xffff0000u) * wA;
    a2 += __uint_as_float(vA.y << 16) * wA;
    a3 += __uint_as_float(vA.y & 0xffff0000u) * wA;
    a4 += __uint_as_float(vA.z << 16) * wA;
    a5 += __uint_as_float(vA.z & 0xffff0000u) * wA;
    a6 += __uint_as_float(vA.w << 16) * wA;
    a7 += __uint_as_float(vA.w & 0xffff0000u) * wA;
    a0 += __uint_as_float(vB.x << 16) * wB;
    a1 += __uint_as_float(vB.x & 0xffff0000u) * wB;
    a2 += __uint_as_float(vB.y << 16) * wB;
    a3 += __uint_as_float(vB.y & 0xffff0000u) * wB;
    a4 += __uint_as_float(vB.z << 16) * wB;
    a5 += __uint_as_float(vB.z & 0xffff0000u) * wB;
    a6 += __uint_as_float(vB.w << 16) * wB;
    a7 += __uint_as_float(vB.w & 0xffff0000u) * wB;
  }
  if (j < deg) {
    unsigned mA = mp[j];
    uint4 vA = *(const uint4*)(fb + (mA & 0xffffu) * 128u + coff);
    float wA = __half2float(__ushort_as_half((unsigned short)(mA >> 16)));
    a0 += __uint_as_float(vA.x << 16) * wA;
    a1 += __uint_as_float(vA.x & 0xffff0000u) * wA;
    a2 += __uint_as_float(vA.y << 16) * wA;
    a3 += __uint_as_float(vA.y & 0xffff0000u) * wA;
    a4 += __uint_as_float(vA.z << 16) * wA;
    a5 += __uint_as_float(vA.z & 0xffff0000u) * wA;
    a6 += __uint_as_float(vA.w << 16) * wA;
    a7 += __uint_as_float(vA.w & 0xffff0000u) * wA;
  }
  short8 o;
  o[0] = (short)f2bf(a0); o[1] = (short)f2bf(a1); o[2] = (short)f2bf(a2); o[3] = (short)f2bf(a3);
  o[4] = (short)f2bf(a4); o[5] = (short)f2bf(a5); o[6] = (short)f2bf(a6); o[7] = (short)f2bf(a7);
  *(short8*)(outp + (size_t)panel * PSTRIDE + (size_t)node * 64 + c8 * 8) = o;
}

// ---------------- bf16 MFMA GEMM (A operands PANEL-MAJOR): h1p = relu([A0|A1]@BT^T + b)
__global__ __launch_bounds__(256, 3)
void gemm_bt_relu(const short* __restrict__ A0, const short* __restrict__ A1,
                  const short* __restrict__ BT, const float* __restrict__ bias,
                  unsigned short* __restrict__ Outp, int M, int S) {
  const int K = 2 * S;
  __shared__ __align__(16) short As[128 * 64];
  __shared__ __align__(16) short Bs[128 * 64];
  const int m0 = blockIdx.x * 128;
  const int n0 = blockIdx.y * 128;
  const int tid = threadIdx.x;
  const int wave = tid >> 6;
  const int lane = tid & 63;
  const int quad = lane >> 4;
  const int r = lane & 15;
  const int wm = (wave >> 1) * 64;
  const int wn = (wave & 1) * 64;

  f32x4 acc[4][4] = {};

  const int nk = K >> 6;
  for (int kt = 0; kt < nk; ++kt) {
    const int kbase = kt << 6;
    const short* Ab;
    int koff;
    if (kbase < S) { Ab = A0; koff = kbase; } else { Ab = A1; koff = kbase - S; }
    const short* Apan = Ab + (size_t)(koff >> 6) * PSTRIDE;
#pragma unroll
    for (int i = 0; i < 4; ++i) {
      int s = ((wave * 4 + i) << 6) + lane;
      int row = s >> 3;
      int c = (s & 7) ^ (row & 7);
      int rg = m0 + row; if (rg > M - 1) rg = M - 1;
      const short* gp = Apan + (size_t)rg * 64 + (c << 3);
      __builtin_amdgcn_global_load_lds((const __attribute__((address_space(1))) void*)gp,
                                       (__attribute__((address_space(3))) void*)&As[(wave * 4 + i) * 512],
                                       16, 0, 0);
    }
#pragma unroll
    for (int i = 0; i < 4; ++i) {
      int s = ((wave * 4 + i) << 6) + lane;
      int row = s >> 3;
      int c = (s & 7) ^ (row & 7);
      const short* gp = BT + (size_t)(n0 + row) * K + kbase + (c << 3);
      __builtin_amdgcn_global_load_lds((const __attribute__((address_space(1))) void*)gp,
                                       (__attribute__((address_space(3))) void*)&Bs[(wave * 4 + i) * 512],
                                       16, 0, 0);
    }
    __syncthreads();
#pragma unroll
    for (int ks = 0; ks < 2; ++ks) {
      short8 af[4], bfr[4];
#pragma unroll
      for (int tm = 0; tm < 4; ++tm) {
        int ml = wm + tm * 16 + r;
        int c = (ks << 2) + quad;
        int slot = ml * 8 + (c ^ (ml & 7));
        af[tm] = *(const short8*)&As[slot * 8];
      }
#pragma unroll
      for (int tn = 0; tn < 4; ++tn) {
        int nl = wn + tn * 16 + r;
        int c = (ks << 2) + quad;
        int slot = nl * 8 + (c ^ (nl & 7));
        bfr[tn] = *(const short8*)&Bs[slot * 8];
      }
#pragma unroll
      for (int tm = 0; tm < 4; ++tm)
#pragma unroll
        for (int tn = 0; tn < 4; ++tn)
          acc[tm][tn] = __builtin_amdgcn_mfma_f32_16x16x32_bf16(af[tm], bfr[tn], acc[tm][tn], 0, 0, 0);
    }
    __syncthreads();
  }

#pragma unroll
  for (int tm = 0; tm < 4; ++tm) {
    int rowb = m0 + wm + tm * 16 + quad * 4;
#pragma unroll
    for (int tn = 0; tn < 4; ++tn) {
      int col = n0 + wn + tn * 16 + r;
      float bv = bias[col];
      unsigned short* obase = Outp + (size_t)(col >> 6) * PSTRIDE + (col & 63);
#pragma unroll
      for (int reg = 0; reg < 4; ++reg) {
        int rr = rowb + reg;
        if (rr < M) {
          float v = acc[tm][tn][reg] + bv;
          v = v > 0.f ? v : 0.f;
          obase[(size_t)rr * 64] = f2bf(v);
        }
      }
    }
  }
}

// ---------------- GEMM2 + fused mean-pool (A panel-major): gsum += per-graph col sums
__global__ __launch_bounds__(256, 3)
void gemm_bt_pool(const short* __restrict__ A0, const short* __restrict__ A1,
                  const short* __restrict__ BT, const float* __restrict__ bias,
                  const int* __restrict__ batch, float* __restrict__ gsum, int M, int S) {
  const int K = 2 * S;
  __shared__ __align__(16) short As[128 * 64];
  __shared__ __align__(16) short Bs[128 * 64];
  const int m0 = blockIdx.x * 128;
  const int n0 = blockIdx.y * 128;
  const int tid = threadIdx.x;
  const int wave = tid >> 6;
  const int lane = tid & 63;
  const int quad = lane >> 4;
  const int r = lane & 15;
  const int wm = (wave >> 1) * 64;
  const int wn = (wave & 1) * 64;

  f32x4 acc[4][4] = {};

  const int nk = K >> 6;
  for (int kt = 0; kt < nk; ++kt) {
    const int kbase = kt << 6;
    const short* Ab;
    int koff;
    if (kbase < S) { Ab = A0; koff = kbase; } else { Ab = A1; koff = kbase - S; }
    const short* Apan = Ab + (size_t)(koff >> 6) * PSTRIDE;
#pragma unroll
    for (int i = 0; i < 4; ++i) {
      int s = ((wave * 4 + i) << 6) + lane;
      int row = s >> 3;
      int c = (s & 7) ^ (row & 7);
      int rg = m0 + row; if (rg > M - 1) rg = M - 1;
      const short* gp = Apan + (size_t)rg * 64 + (c << 3);
      __builtin_amdgcn_global_load_lds((const __attribute__((address_space(1))) void*)gp,
                                       (__attribute__((address_space(3))) void*)&As[(wave * 4 + i) * 512],
                                       16, 0, 0);
    }
#pragma unroll
    for (int i = 0; i < 4; ++i) {
      int s = ((wave * 4 + i) << 6) + lane;
      int row = s >> 3;
      int c = (s & 7) ^ (row & 7);
      const short* gp = BT + (size_t)(n0 + row) * K + kbase + (c << 3);
      __builtin_amdgcn_global_load_lds((const __attribute__((address_space(1))) void*)gp,
                                       (__attribute__((address_space(3))) void*)&Bs[(wave * 4 + i) * 512],
                                       16, 0, 0);
    }
    __syncthreads();
#pragma unroll
    for (int ks = 0; ks < 2; ++ks) {
      short8 af[4], bfr[4];
#pragma unroll
      for (int tm = 0; tm < 4; ++tm) {
        int ml = wm + tm * 16 + r;
        int c = (ks << 2) + quad;
        int slot = ml * 8 + (c ^ (ml & 7));
        af[tm] = *(const short8*)&As[slot * 8];
      }
#pragma unroll
      for (int tn = 0; tn < 4; ++tn) {
        int nl = wn + tn * 16 + r;
        int c = (ks << 2) + quad;
        int slot = nl * 8 + (c ^ (nl & 7));
        bfr[tn] = *(const short8*)&Bs[slot * 8];
      }
#pragma unroll
      for (int tm = 0; tm < 4; ++tm)
#pragma unroll
        for (int tn = 0; tn < 4; ++tn)
          acc[tm][tn] = __builtin_amdgcn_mfma_f32_16x16x32_bf16(af[tm], bfr[tn], acc[tm][tn], 0, 0, 0);
    }
    __syncthreads();
  }

  // epilogue: relu(+bias), zero invalid rows, per-graph column sums -> atomicAdd(gsum)
  int gid[4][4];
#pragma unroll
  for (int tm = 0; tm < 4; ++tm) {
    int rowb = m0 + wm + tm * 16 + quad * 4;
#pragma unroll
    for (int reg = 0; reg < 4; ++reg) {
      int rr = rowb + reg;
      gid[tm][reg] = batch[rr < M ? rr : (M - 1)];
    }
#pragma unroll
    for (int tn = 0; tn < 4; ++tn) {
      float bv = bias[n0 + wn + tn * 16 + r];
#pragma unroll
      for (int reg = 0; reg < 4; ++reg) {
        int rr = rowb + reg;
        float v = acc[tm][tn][reg] + bv;
        v = v > 0.f ? v : 0.f;
        acc[tm][tn][reg] = (rr < M) ? v : 0.f;
      }
    }
  }
  int g_lo = batch[m0 < M ? m0 : (M - 1)];
  int g_hi = batch[(m0 + 127) < M ? (m0 + 127) : (M - 1)];
  for (int g = g_lo; g <= g_hi; ++g) {
#pragma unroll
    for (int tn = 0; tn < 4; ++tn) {
      float s = 0.f;
#pragma unroll
      for (int tm = 0; tm < 4; ++tm)
#pragma unroll
        for (int reg = 0; reg < 4; ++reg)
          s += (gid[tm][reg] == g) ? acc[tm][tn][reg] : 0.f;
      s += __shfl_xor(s, 16);
      s += __shfl_xor(s, 32);
      if (quad == 0)
        atomicAdd(&gsum[(size_t)g * HIDC + n0 + wn + tn * 16 + r], s);
    }
  }
}

// ---------------- MLP head (256 threads: 4-way split over the 512-dim input)
__global__ __launch_bounds__(256)
void mlp_kernel(const float* __restrict__ gsum, const int* __restrict__ batch,
                const float* __restrict__ Wl1, const float* __restrict__ bl1,
                const float* __restrict__ Wl2, const float* __restrict__ bl2,
                const float* __restrict__ Wl3, const float* __restrict__ bl3,
                float* __restrict__ out) {
  int gi = blockIdx.x;
  int t = threadIdx.x;
  int unit = t & 63;
  int part = t >> 6;  // 4 parts of 128
  __shared__ float red[4][64];
  __shared__ float h1s[64];
  __shared__ float h2s[16];
  int lo = 0, hi = N_NODESC;
  while (lo < hi) { int mid = (lo + hi) >> 1; if (batch[mid] < gi) lo = mid + 1; else hi = mid; }
  int start = lo;
  hi = N_NODESC;
  while (lo < hi) { int mid = (lo + hi) >> 1; if (batch[mid] < gi + 1) lo = mid + 1; else hi = mid; }
  float inv = 1.0f / fmaxf((float)(lo - start), 1.0f);
  const float* gr = gsum + gi * HIDC;
  float acc = 0.f;
  for (int j = part * 128; j < (part + 1) * 128; ++j)
    acc += gr[j] * Wl1[j * 64 + unit];
  red[part][unit] = acc;
  __syncthreads();
  if (t < 64) {
    float a = bl1[t] + (red[0][t] + red[1][t] + red[2][t] + red[3][t]) * inv;
    h1s[t] = fmaxf(a, 0.f);
  }
  __syncthreads();
  if (t < 16) {
    float a = bl2[t];
    for (int j = 0; j < 64; ++j) a += h1s[j] * Wl2[j * 16 + t];
    h2s[t] = fmaxf(a, 0.f);
  }
  __syncthreads();
  if (t == 0) {
    float a = bl3[0];
    for (int j = 0; j < 16; ++j) a += h2s[j] * Wl3[j];
    out[gi] = a;
  }
}

extern "C" void kernel_launch(void* const* d_in, const int* in_sizes, int n_in,
                              void* d_out, int out_size, void* d_ws, size_t ws_size,
                              hipStream_t stream) {
  const float* x      = (const float*)d_in[0];
  const int*   ei     = (const int*)d_in[1];
  const float* ea     = (const float*)d_in[2];
  const int*   batch  = (const int*)d_in[3];
  const float* W1rel  = (const float*)d_in[4];
  const float* b1     = (const float*)d_in[5];
  const float* W1root = (const float*)d_in[6];
  const float* W2rel  = (const float*)d_in[7];
  const float* b2     = (const float*)d_in[8];
  const float* W2root = (const float*)d_in[9];
  const float* Wl1    = (const float*)d_in[10];
  const float* bl1    = (const float*)d_in[11];
  const float* Wl2    = (const float*)d_in[12];
  const float* bl2    = (const float*)d_in[13];
  const float* Wl3    = (const float*)d_in[14];
  const float* bl3    = (const float*)d_in[15];
  float* out = (float*)d_out;

  // workspace layout (bytes, 16B-aligned). All node features PANEL-MAJOR [P][25000][64].
  char* ws = (char*)d_ws;
  unsigned short* xp     = (unsigned short*)(ws + 0);           //  6.4 MB (2 panels)
  unsigned short* agg1p  = (unsigned short*)(ws + 6400000);     //  6.4 MB (2 panels)
  unsigned short* h1p    = (unsigned short*)(ws + 12800000);    // 25.6 MB (8 panels)
  unsigned short* agg2p  = (unsigned short*)(ws + 38400000);    // 25.6 MB (8 panels)
  unsigned short* W1T    = (unsigned short*)(ws + 64000000);    // 256 KB
  unsigned short* W2T    = (unsigned short*)(ws + 64262144);    //   1 MB
  float*          gsum   = (float*)(ws + 65310720);             // 128 KB
  int*            deg    = (int*)(ws + 65441792);               // 100 KB
  int*            cursor = (int*)(ws + 65541792);               // 100 KB
  int*            indptr = (int*)(ws + 65641792);               // 100 KB+16
  unsigned*       emeta  = (unsigned*)(ws + 65741808);          //  1.6 MB (exact CSR)
  int*            sorted = (int*)(ws + 67341808);               // 100 KB

  // 0) prep (zero deg+gsum, x->bf16 panels) + weight transposes + CSR build + deg-sort
  prep_kernel<<<3351, 256, 0, stream>>>(x, xp, deg, gsum);
  wt_kernel<<<160, 256, 0, stream>>>(W1rel, W1root, W2rel, W2root, W1T, W2T);
  deg_kernel<<<(N_EDGESC + 255) / 256, 256, 0, stream>>>(ei, deg);
  scan_kernel<<<1, 1024, 0, stream>>>(deg, indptr, cursor, sorted);
  fill_kernel<<<(N_EDGESC + 255) / 256, 256, 0, stream>>>(ei, ea, cursor, emeta);

  // 1) layer-1 aggregation: 2 panels (panel = blk&1); 32 nodes/block
  const int NBLK = (N_NODESC + 31) / 32;   // 782
  agg_gather_s<<<NBLK * 2, 256, 0, stream>>>(xp, indptr, emeta, sorted, agg1p, 1);

  // 2) GEMM1: h1p = relu([agg1|x] @ [W1rel;W1root] + b1)   (M=25000, K=256, N=512)
  dim3 gg((N_NODESC + 127) / 128, 4);
  gemm_bt_relu<<<gg, 256, 0, stream>>>((const short*)agg1p, (const short*)xp,
                                       (const short*)W1T, b1, h1p, N_NODESC, 128);

  // 3) layer-2 aggregation: 8 panels (panel = blk&7 -> one panel per XCD, 3.2MB L2-resident)
  agg_gather_s<<<NBLK * 8, 256, 0, stream>>>(h1p, indptr, emeta, sorted, agg2p, 3);

  // 4) GEMM2 + fused mean-pool
  gemm_bt_pool<<<gg, 256, 0, stream>>>((const short*)agg2p, (const short*)h1p,
                                       (const short*)W2T, b2, batch, gsum, N_NODESC, 512);

  // 5) MLP head (divides by counts)
  mlp_kernel<<<N_GRAPHSC, 256, 0, stream>>>(gsum, batch, Wl1, bl1, Wl2, bl2, Wl3, bl3, out);
}